// Round 8
// baseline (4067.429 us; speedup 1.0000x reference)
//
#include <hip/hip_runtime.h>
#include <hip/hip_bf16.h>
#include <hip/hip_fp16.h>

// ---------------------------------------------------------------------------
// Encoder: mean = APPNP(normalize(x@lin_w+b)*1.8), logstd = attention-pooled
// graph-wavelet branch.
// Round 8: two-phase bucketed CSR build (phase A: LDS-batched coalesced
// bucket staging; phase B: L2-local scatter) fused into the gather pipeline:
// F_j = gather(j-1) || B(j) || A(j+1) || hist(j+2).
// ---------------------------------------------------------------------------

typedef unsigned long long ull;
#define NBMAX 32
#define BSH 12            // bucket = 4096 rows
#define BATCH 2048        // phase-A batch (8 edges/thread)

// ---------- standalone histogram (int atomics) ----------
__global__ __launch_bounds__(256) void hist_kernel(const int* __restrict__ idx,
                                                   int* __restrict__ cnt, int n) {
    int i = blockIdx.x * 256 + threadIdx.x;
    if (i < n) atomicAdd(&cnt[__builtin_nontemporal_load(idx + i)], 1);
}

// dinv from degree; zeroes cnt for the next histogram
__global__ __launch_bounds__(256) void dinv_kernel(int* __restrict__ cnt,
                                                   float* __restrict__ dinv, int n) {
    int i = blockIdx.x * 256 + threadIdx.x;
    if (i < n) { dinv[i] = rsqrtf((float)(cnt[i] + 1)); cnt[i] = 0; }
}

// ---------- 3-kernel exclusive scan of cnt[N] -> ptr[N+1] ----------
__global__ __launch_bounds__(256) void scan_reduce_kernel(
    const int* __restrict__ cnt, int* __restrict__ bsum, int N) {
    __shared__ int wsum[4];
    int base = blockIdx.x * 1024;
    int t = threadIdx.x;
    int s = 0;
#pragma unroll
    for (int j = 0; j < 4; ++j) {
        int idx = base + t * 4 + j;
        if (idx < N) s += cnt[idx];
    }
#pragma unroll
    for (int off = 32; off; off >>= 1) s += __shfl_xor(s, off);
    int lane = t & 63, w = t >> 6;
    if (lane == 0) wsum[w] = s;
    __syncthreads();
    if (t == 0) bsum[blockIdx.x] = wsum[0] + wsum[1] + wsum[2] + wsum[3];
}

__global__ void scan_bsum_kernel(const int* __restrict__ bsum,
                                 int* __restrict__ bofs,
                                 int* __restrict__ ptr, int nblk, int N) {
    if (threadIdx.x == 0 && blockIdx.x == 0) {
        int run = 0;
        for (int i = 0; i < nblk; ++i) { bofs[i] = run; run += bsum[i]; }
        bofs[nblk] = run;
        ptr[N] = run;
    }
}

// writes ptr/cursor AND zeroes cnt for the next histogram
__global__ __launch_bounds__(256) void scan_block_kernel(
    int* __restrict__ cnt, const int* __restrict__ bofs,
    int* __restrict__ ptr, int* __restrict__ cursor, int N) {
    __shared__ int wsum[4];
    int base = blockIdx.x * 1024;
    int t = threadIdx.x, lane = t & 63, w = t >> 6;
    int v[4]; int s = 0;
#pragma unroll
    for (int j = 0; j < 4; ++j) {
        int idx = base + t * 4 + j;
        v[j] = (idx < N) ? cnt[idx] : 0;
        s += v[j];
    }
    int incl = s;
#pragma unroll
    for (int off = 1; off < 64; off <<= 1) {
        int nn = __shfl_up(incl, off);
        if (lane >= off) incl += nn;
    }
    if (lane == 63) wsum[w] = incl;
    __syncthreads();
    int wofs = 0;
    for (int i = 0; i < w; ++i) wofs += wsum[i];
    int run = bofs[blockIdx.x] + wofs + incl - s;
#pragma unroll
    for (int j = 0; j < 4; ++j) {
        int idx = base + t * 4 + j;
        if (idx < N) { ptr[idx] = run; cursor[idx] = run; cnt[idx] = 0; }
        run += v[j];
    }
}

// bcur[b] = ptr[min(b<<BSH, N)] -- phase-A bucket write cursors
__global__ void bcur_init_kernel(const int* __restrict__ ptr,
                                 int* __restrict__ bcur, int N, int nb) {
    int b = threadIdx.x;
    if (b < nb) bcur[b] = ptr[min(b << BSH, N)];
}

// ---------- fused pipeline: gather(k-1) || phaseB(k) || phaseA(k+1) || hist(k+2)
// staging u64: [rowlo:12 @49][col:17 @32][valbits:32]
// cpair u64:   [valbits:32 @32][col:32]  (int2: x=col, y=val)
__global__ __launch_bounds__(256) void fused2_kernel(
    // G role
    const int* __restrict__ ptr_g, const int2* __restrict__ cpair_g,
    const __half* __restrict__ srch, const float* __restrict__ srcf,
    const float* __restrict__ init_src, const float* __restrict__ dinv,
    float* __restrict__ dstf, __half* __restrict__ dsth, int N, int nnz_g,
    // B role (phase B)
    const ull* __restrict__ stg_in, const int* __restrict__ ptr_b,
    int* __restrict__ cursor_b, ull* __restrict__ cpair_out, int nnz_b, int nb,
    // A role (phase A)
    const int* __restrict__ rows_a, const int* __restrict__ cols_a,
    const float* __restrict__ vals_a, const float* __restrict__ diag,
    int mode_a, int* __restrict__ bcur_a, ull* __restrict__ stg_out, int nnz_a,
    // H role
    const int* __restrict__ rows_h, int* __restrict__ cnt, int nnz_h,
    int mix)
{
    __shared__ ull stg[BATCH];
    __shared__ int lcnt[NBMAX], lofs_s[NBMAX], gbase[NBMAX];
    __shared__ int bstartL[NBMAX + 1];

    int role, lid, nloc;   // 0=H 1=B 2=A 3=G
    if (mix == 0) { role = 3; lid = blockIdx.x; nloc = gridDim.x; }
    else {
        int r = blockIdx.x & 15, g = blockIdx.x >> 4, ng = gridDim.x >> 4;
        if (mix == 1) {
            if (r < 9)       { role = 3; lid = g * 9 + r;        nloc = ng * 9; }
            else if (r < 12) { role = 1; lid = g * 3 + (r - 9);  nloc = ng * 3; }
            else if (r < 15) { role = 2; lid = g * 3 + (r - 12); nloc = ng * 3; }
            else             { role = 0; lid = g;                nloc = ng; }
        } else if (mix == 2) {
            if (r < 14) { role = 2; lid = g * 14 + r;        nloc = ng * 14; }
            else        { role = 0; lid = g * 2 + (r - 14);  nloc = ng * 2; }
        } else { // 3
            if (r < 8)       { role = 1; lid = g * 8 + r;        nloc = ng * 8; }
            else if (r < 14) { role = 2; lid = g * 6 + (r - 8);  nloc = ng * 6; }
            else             { role = 0; lid = g * 2 + (r - 14); nloc = ng * 2; }
        }
    }
    const int t = threadIdx.x;

    if (role == 0) {                       // ---- histogram (op k+2) ----
        if (!rows_h) return;
        int stride = nloc * 256;
        for (int i = lid * 256 + t; i < nnz_h; i += stride)
            atomicAdd(&cnt[__builtin_nontemporal_load(rows_h + i)], 1);
        return;
    }

    if (role == 2) {                       // ---- phase A: bucket staging ----
        if (!rows_a) return;
        for (int base = lid * BATCH; base < nnz_a; base += nloc * BATCH) {
            int cntE = min(BATCH, nnz_a - base);
            if (t < NBMAX) lcnt[t] = 0;
            __syncthreads();
            int myb[8], myo[8]; ull mypk[8];
#pragma unroll
            for (int u = 0; u < 8; ++u) {
                int k = t + u * 256;
                if (k < cntE) {
                    int idx = base + k;
                    int r = __builtin_nontemporal_load(rows_a + idx);
                    int c = __builtin_nontemporal_load(cols_a + idx);
                    float v;
                    if (mode_a == 2) v = dinv[r] * dinv[c];
                    else {
                        v = __builtin_nontemporal_load(vals_a + idx);
                        if (mode_a == 1) v *= diag[c];
                    }
                    int b = r >> BSH;
                    myb[u] = b;
                    myo[u] = atomicAdd(&lcnt[b], 1);
                    mypk[u] = ((ull)(r & ((1 << BSH) - 1)) << 49) |
                              ((ull)(unsigned)c << 32) | (unsigned)__float_as_uint(v);
                }
            }
            __syncthreads();
            if (t == 0) {
                int run = 0;
                for (int b = 0; b < NBMAX; ++b) { lofs_s[b] = run; run += lcnt[b]; }
            }
            __syncthreads();
            if (t < NBMAX && lcnt[t] > 0) gbase[t] = atomicAdd(&bcur_a[t], lcnt[t]);
            __syncthreads();
#pragma unroll
            for (int u = 0; u < 8; ++u) {
                int k = t + u * 256;
                if (k < cntE) stg[lofs_s[myb[u]] + myo[u]] = mypk[u];
            }
            __syncthreads();
            for (int i = t; i < cntE; i += 256) {
                int lo = 0, hi = NBMAX - 1;        // largest b: lofs_s[b] <= i
                while (lo < hi) { int mid = (lo + hi + 1) >> 1;
                                  if (lofs_s[mid] <= i) lo = mid; else hi = mid - 1; }
                stg_out[gbase[lo] + (i - lofs_s[lo])] = stg[i];
            }
            __syncthreads();
        }
        return;
    }

    if (role == 1) {                       // ---- phase B: L2-local scatter ----
        if (!stg_in) return;
        if (t <= NBMAX) bstartL[t] = ptr_b[min(t << BSH, N)];
        __syncthreads();
        int stride = nloc * 256;
        for (int i = lid * 256 + t; i < nnz_b; i += stride) {
            ull p = stg_in[i];
            int lo = 0, hi = nb - 1;               // largest b: bstartL[b] <= i
            while (lo < hi) { int mid = (lo + hi + 1) >> 1;
                              if (bstartL[mid] <= i) lo = mid; else hi = mid - 1; }
            int row = (lo << BSH) | (int)(p >> 49);
            unsigned c = (unsigned)(p >> 32) & 0x1FFFFu;
            unsigned vbits = (unsigned)p;
            int pos = atomicAdd(&cursor_b[row], 1);
            cpair_out[pos] = ((ull)vbits << 32) | c;
        }
        return;
    }

    // ---- G role: gather spmm, wave per row ----
    if (!ptr_g) return;
    const int lane = t & 63;
    const size_t lofs = (size_t)(lane * 2);
    int wid = (lid * 256 + t) >> 6;
    const int nwaves = (nloc * 256) >> 6;
    for (int row = wid; row < N; row += nwaves) {
        int s = ptr_g[row], e = ptr_g[row + 1];
        e = min(e, nnz_g); s = max(0, min(s, e));   // bad CSR must not fault
        float accx = 0.f, accy = 0.f;
        if (init_src) {
            float d = dinv[row];
            float dd = d * d;
            float2 m = *(const float2*)(init_src + (size_t)row * 128 + lofs);
            accx = dd * m.x; accy = dd * m.y;
        }
        for (int base = s; base < e; base += 64) {
            int n = min(64, e - base);
            int2 p = make_int2(0, 0);
            if (lane < n) p = cpair_g[base + lane];
            int j = 0;
            if (srch) {
                for (; j + 16 <= n; j += 16) {
                    __half2 sv[16]; float vj[16];
#pragma unroll
                    for (int u = 0; u < 16; ++u) {
                        int cj = __builtin_amdgcn_readlane(p.x, j + u);
                        vj[u] = __int_as_float(__builtin_amdgcn_readlane(p.y, j + u));
                        sv[u] = *(const __half2*)(srch + (size_t)cj * 128 + lofs);
                    }
#pragma unroll
                    for (int u = 0; u < 16; ++u) {
                        accx += vj[u] * __low2float(sv[u]);
                        accy += vj[u] * __high2float(sv[u]);
                    }
                }
                for (; j < n; ++j) {
                    int cj = __builtin_amdgcn_readlane(p.x, j);
                    float vj = __int_as_float(__builtin_amdgcn_readlane(p.y, j));
                    __half2 sv = *(const __half2*)(srch + (size_t)cj * 128 + lofs);
                    accx += vj * __low2float(sv);
                    accy += vj * __high2float(sv);
                }
            } else {
                for (; j + 8 <= n; j += 8) {
                    float2 sv[8]; float vj[8];
#pragma unroll
                    for (int u = 0; u < 8; ++u) {
                        int cj = __builtin_amdgcn_readlane(p.x, j + u);
                        vj[u] = __int_as_float(__builtin_amdgcn_readlane(p.y, j + u));
                        sv[u] = *(const float2*)(srcf + (size_t)cj * 128 + lofs);
                    }
#pragma unroll
                    for (int u = 0; u < 8; ++u) {
                        accx += vj[u] * sv[u].x;
                        accy += vj[u] * sv[u].y;
                    }
                }
                for (; j < n; ++j) {
                    int cj = __builtin_amdgcn_readlane(p.x, j);
                    float vj = __int_as_float(__builtin_amdgcn_readlane(p.y, j));
                    float2 sv = *(const float2*)(srcf + (size_t)cj * 128 + lofs);
                    accx += vj * sv.x;
                    accy += vj * sv.y;
                }
            }
        }
        if (dstf) {
            float2 o; o.x = accx; o.y = accy;
            *(float2*)(dstf + (size_t)row * 128 + lofs) = o;
        }
        if (dsth) {
            *(__half2*)(dsth + (size_t)row * 128 + lofs) =
                __floats2half2_rn(accx, accy);
        }
    }
}

// ---------- fused dual GEMM: mean0(fp32) = x@lin_w + b, xw(fp16) = x@gw_w ---
__global__ __launch_bounds__(256) void gemm_fused(
    const float* __restrict__ x, const float* __restrict__ lin_w,
    const float* __restrict__ lin_b, const float* __restrict__ gw_w,
    float* __restrict__ mean0, __half* __restrict__ xwh, int M) {
    __shared__ float As[32][68];
    __shared__ float Bs[32][64];
    const int tid = threadIdx.x;
    const int tx = tid & 15, ty = tid >> 4;
    const int row0 = blockIdx.x * 64;
    const int nt = blockIdx.y;
    const float* __restrict__ W = (nt < 2) ? lin_w : gw_w;
    const int colbase = (nt & 1) * 64;

    const int ar = tid >> 3;
    const int ac = (tid & 7) << 2;
    const int bk = tid >> 4;
    const int bn = (tid & 15) << 2;

    float acc[4][4] = {};

    for (int kt = 0; kt < 256; kt += 32) {
#pragma unroll
        for (int rr = 0; rr < 2; ++rr) {
            int r = ar + rr * 32;
            int grow = row0 + r;
            float4 v = make_float4(0.f, 0.f, 0.f, 0.f);
            if (grow < M) v = *(const float4*)(x + (size_t)grow * 256 + kt + ac);
            As[ac + 0][r] = v.x; As[ac + 1][r] = v.y;
            As[ac + 2][r] = v.z; As[ac + 3][r] = v.w;
        }
#pragma unroll
        for (int rr = 0; rr < 2; ++rr) {
            int k = bk + rr * 16;
            *(float4*)&Bs[k][bn] =
                *(const float4*)(W + (size_t)(kt + k) * 128 + colbase + bn);
        }
        __syncthreads();
#pragma unroll
        for (int k = 0; k < 32; ++k) {
            float4 a = *(const float4*)&As[k][ty * 4];
            float4 b = *(const float4*)&Bs[k][tx * 4];
            float av[4] = {a.x, a.y, a.z, a.w};
            float bv[4] = {b.x, b.y, b.z, b.w};
#pragma unroll
            for (int i = 0; i < 4; ++i)
#pragma unroll
                for (int j = 0; j < 4; ++j) acc[i][j] += av[i] * bv[j];
        }
        __syncthreads();
    }

    if (nt < 2) {
        float4 bb = *(const float4*)(lin_b + colbase + tx * 4);
#pragma unroll
        for (int i = 0; i < 4; ++i) {
            int grow = row0 + ty * 4 + i;
            if (grow < M) {
                float4 o = make_float4(acc[i][0] + bb.x, acc[i][1] + bb.y,
                                       acc[i][2] + bb.z, acc[i][3] + bb.w);
                *(float4*)(mean0 + (size_t)grow * 128 + colbase + tx * 4) = o;
            }
        }
    } else {
#pragma unroll
        for (int i = 0; i < 4; ++i) {
            int grow = row0 + ty * 4 + i;
            if (grow < M) {
                union { __half2 h[2]; int2 i2; } u;
                u.h[0] = __floats2half2_rn(acc[i][0], acc[i][1]);
                u.h[1] = __floats2half2_rn(acc[i][2], acc[i][3]);
                *(int2*)(xwh + (size_t)grow * 128 + colbase + tx * 4) = u.i2;
            }
        }
    }
}

// ---------- row L2-normalize * 1.8, in place (wave per row) ----------
__global__ __launch_bounds__(256) void rownorm_kernel(float* __restrict__ m, int n) {
    const int lane = threadIdx.x & 63;
    int wid = (blockIdx.x * 256 + threadIdx.x) >> 6;
    if (wid >= n) return;
    float2 v = *(float2*)(m + (size_t)wid * 128 + lane * 2);
    float ss = v.x * v.x + v.y * v.y;
#pragma unroll
    for (int off = 32; off; off >>= 1) ss += __shfl_xor(ss, off);
    float s = sqrtf(ss);
    float sc = 1.8f / fmaxf(s, 1e-12f);
    v.x *= sc; v.y *= sc;
    *(float2*)(m + (size_t)wid * 128 + lane * 2) = v;
}

// ---------- attention pool, fp16 z0/z1 + fp32 z2, in-place on z2 ----------
__global__ __launch_bounds__(256) void attn_h_kernel(
    const __half* __restrict__ z0, const __half* __restrict__ z1,
    const float* __restrict__ z2, const float* __restrict__ w1,
    const float* __restrict__ b1, const float* __restrict__ w2,
    float* __restrict__ out, int n) {
    const int lane = threadIdx.x & 63;
    float w1reg[128];
#pragma unroll
    for (int d = 0; d < 128; ++d) w1reg[d] = w1[d * 64 + lane];
    const float b1l = b1[lane];
    const float w2l = w2[lane];

    int wid = (blockIdx.x * 256 + threadIdx.x) >> 6;
    const int nwaves = (gridDim.x * 256) >> 6;
    for (int node = wid; node < n; node += nwaves) {
        float2 za = __half22float2(*(const __half2*)(z0 + (size_t)node * 128 + lane * 2));
        float2 zb = __half22float2(*(const __half2*)(z1 + (size_t)node * 128 + lane * 2));
        float2 zc = *(const float2*)(z2 + (size_t)node * 128 + lane * 2);
        float wk[3];
#pragma unroll
        for (int k = 0; k < 3; ++k) {
            float zx = (k == 0) ? za.x : (k == 1) ? zb.x : zc.x;
            float zy = (k == 0) ? za.y : (k == 1) ? zb.y : zc.y;
            float acc = 0.f;
#pragma unroll
            for (int d2 = 0; d2 < 64; ++d2) {
                float ze = __uint_as_float(__builtin_amdgcn_readlane(__float_as_uint(zx), d2));
                float zo = __uint_as_float(__builtin_amdgcn_readlane(__float_as_uint(zy), d2));
                acc += ze * w1reg[2 * d2] + zo * w1reg[2 * d2 + 1];
            }
            float h = fmaxf(acc + b1l, 0.f) * w2l;
#pragma unroll
            for (int off = 32; off; off >>= 1) h += __shfl_xor(h, off);
            wk[k] = h;
        }
        float mx = fmaxf(wk[0], fmaxf(wk[1], wk[2]));
        float e0 = __expf(wk[0] - mx);
        float e1 = __expf(wk[1] - mx);
        float e2 = __expf(wk[2] - mx);
        float inv = 1.f / (e0 + e1 + e2);
        float be0 = e0 * inv, be1 = e1 * inv, be2 = e2 * inv;
        float2 o;
        o.x = be0 * za.x + be1 * zb.x + be2 * zc.x;
        o.y = be0 * za.y + be1 * zb.y + be2 * zc.y;
        *(float2*)(out + (size_t)node * 128 + lane * 2) = o;
    }
}

// ---------- fallback-only kernels ----------
__global__ __launch_bounds__(256) void f2h_kernel(const float* __restrict__ in,
                                                  __half* __restrict__ out,
                                                  size_t n2) {
    size_t i = (size_t)blockIdx.x * 256 + threadIdx.x;
    if (i >= n2) return;
    float2 v = ((const float2*)in)[i];
    ((__half2*)out)[i] = __floats2half2_rn(v.x, v.y);
}

__global__ __launch_bounds__(256) void spmm_h_kernel(
    const int* __restrict__ rows, const int* __restrict__ cols,
    const float* __restrict__ vals, const float* __restrict__ diag,
    const __half* __restrict__ src, float* __restrict__ dst, int nnz) {
    const int lane = threadIdx.x & 63;
    int wid = (blockIdx.x * 256 + threadIdx.x) >> 6;
    const int nwaves = (gridDim.x * 256) >> 6;
    for (int e = wid; e < nnz; e += nwaves) {
        int r = rows[e];
        int c = cols[e];
        float v = vals ? vals[e] : 1.f;
        if (diag) v *= diag[c];
        __half2 sh = *(const __half2*)(src + (size_t)c * 128 + lane * 2);
        float* d = dst + (size_t)r * 128 + lane * 2;
        unsafeAtomicAdd(d,     v * __low2float(sh));
        unsafeAtomicAdd(d + 1, v * __high2float(sh));
    }
}

__global__ __launch_bounds__(256) void appnp_init_kernel(
    const float* __restrict__ mean0, const float* __restrict__ dinv,
    float* __restrict__ dst, int n) {
    int i = blockIdx.x * 256 + threadIdx.x;
    if (i >= n * 32) return;
    int node = i >> 5;
    float dv = dinv[node];
    float dd = dv * dv;
    float4 v = ((const float4*)mean0)[i];
    v.x *= dd; v.y *= dd; v.z *= dd; v.w *= dd;
    ((float4*)dst)[i] = v;
}

__global__ __launch_bounds__(256) void appnp_edge_h_kernel(
    const int* __restrict__ rows, const int* __restrict__ cols,
    const float* __restrict__ dinv, const __half* __restrict__ src,
    float* __restrict__ dst, int nnz) {
    const int lane = threadIdx.x & 63;
    int wid = (blockIdx.x * 256 + threadIdx.x) >> 6;
    const int nwaves = (gridDim.x * 256) >> 6;
    for (int e = wid; e < nnz; e += nwaves) {
        int r = rows[e];
        int c = cols[e];
        float v = dinv[r] * dinv[c];
        __half2 sh = *(const __half2*)(src + (size_t)c * 128 + lane * 2);
        float* d = dst + (size_t)r * 128 + lane * 2;
        unsafeAtomicAdd(d,     v * __low2float(sh));
        unsafeAtomicAdd(d + 1, v * __high2float(sh));
    }
}

__global__ __launch_bounds__(256) void attn_f_kernel(
    const float* __restrict__ z0, const float* __restrict__ z1,
    const float* __restrict__ z2, const float* __restrict__ w1,
    const float* __restrict__ b1, const float* __restrict__ w2,
    float* __restrict__ out, int n) {
    const int lane = threadIdx.x & 63;
    float w1reg[128];
#pragma unroll
    for (int d = 0; d < 128; ++d) w1reg[d] = w1[d * 64 + lane];
    const float b1l = b1[lane];
    const float w2l = w2[lane];
    int wid = (blockIdx.x * 256 + threadIdx.x) >> 6;
    const int nwaves = (gridDim.x * 256) >> 6;
    for (int node = wid; node < n; node += nwaves) {
        float2 za = *(const float2*)(z0 + (size_t)node * 128 + lane * 2);
        float2 zb = *(const float2*)(z1 + (size_t)node * 128 + lane * 2);
        float2 zc = *(const float2*)(z2 + (size_t)node * 128 + lane * 2);
        float wk[3];
#pragma unroll
        for (int k = 0; k < 3; ++k) {
            float zx = (k == 0) ? za.x : (k == 1) ? zb.x : zc.x;
            float zy = (k == 0) ? za.y : (k == 1) ? zb.y : zc.y;
            float acc = 0.f;
#pragma unroll
            for (int d2 = 0; d2 < 64; ++d2) {
                float ze = __uint_as_float(__builtin_amdgcn_readlane(__float_as_uint(zx), d2));
                float zo = __uint_as_float(__builtin_amdgcn_readlane(__float_as_uint(zy), d2));
                acc += ze * w1reg[2 * d2] + zo * w1reg[2 * d2 + 1];
            }
            float h = fmaxf(acc + b1l, 0.f) * w2l;
#pragma unroll
            for (int off = 32; off; off >>= 1) h += __shfl_xor(h, off);
            wk[k] = h;
        }
        float mx = fmaxf(wk[0], fmaxf(wk[1], wk[2]));
        float e0 = __expf(wk[0] - mx);
        float e1 = __expf(wk[1] - mx);
        float e2 = __expf(wk[2] - mx);
        float inv = 1.f / (e0 + e1 + e2);
        float be0 = e0 * inv, be1 = e1 * inv, be2 = e2 * inv;
        float2 o;
        o.x = be0 * za.x + be1 * zb.x + be2 * zc.x;
        o.y = be0 * za.y + be1 * zb.y + be2 * zc.y;
        *(float2*)(out + (size_t)node * 128 + lane * 2) = o;
    }
}

// ---------------------------------------------------------------------------
extern "C" void kernel_launch(void* const* d_in, const int* in_sizes, int n_in,
                              void* d_out, int out_size, void* d_ws, size_t ws_size,
                              hipStream_t stream)
{
    const float* x            = (const float*)d_in[0];
    const int*   edge_index   = (const int*)d_in[1];    // [2,E]
    const int*   phi_idx      = (const int*)d_in[2];    // [K,2,NNZ]
    const float* phi_vals     = (const float*)d_in[3];  // [K,NNZ]
    const int*   phi_inv_idx  = (const int*)d_in[4];
    const float* phi_inv_vals = (const float*)d_in[5];
    const float* lin_w        = (const float*)d_in[6];
    const float* lin_b        = (const float*)d_in[7];
    const float* gw_w         = (const float*)d_in[8];
    const float* diag_w       = (const float*)d_in[9];
    const float* att_w1       = (const float*)d_in[10];
    const float* att_b1       = (const float*)d_in[11];
    const float* att_w2       = (const float*)d_in[12];

    const int N   = in_sizes[9];
    const int E   = in_sizes[1] / 2;
    const int NNZ = in_sizes[3] / 3;
    const size_t NF = (size_t)N * 128;
    const int MAXNNZ = (E > NNZ) ? E : NNZ;
    const int nblk = (N + 1023) / 1024;
    const int nb = (N + (1 << BSH) - 1) >> BSH;   // coarse buckets

    float* out0 = (float*)d_out;          // final: mean
    float* out1 = out0 + NF;              // final: logstd (temp: mean0, then z2)

    // ---- workspace layout ----
    char* p = (char*)d_ws;
    int*    cnt   = (int*)p;       p += (size_t)N * 4;
    float*  dinv  = (float*)p;     p += (size_t)N * 4;
    __half* xwh   = (__half*)p;    p += NF * 2;
    char* tail = p;
    __half* z0h   = (__half*)p;    p += NF * 2;
    __half* z1h   = (__half*)p;    p += NF * 2;
    __half* t1h   = (__half*)p;    p += NF * 2;
    int*    ptrS[3]; for (int i = 0; i < 3; ++i) { ptrS[i] = (int*)p; p += (size_t)(N + 1) * 4; }
    int*    curS[2]; for (int i = 0; i < 2; ++i) { curS[i] = (int*)p; p += (size_t)N * 4; }
    int*    bsum  = (int*)p;       p += (size_t)nblk * 4;
    int*    bofs  = (int*)p;       p += (size_t)(nblk + 1) * 4;
    int*    bcurS[2]; for (int i = 0; i < 2; ++i) { bcurS[i] = (int*)p; p += NBMAX * 4; }
    p = (char*)(((uintptr_t)p + 7) & ~(uintptr_t)7);
    ull*    stagS[2]; for (int i = 0; i < 2; ++i) { stagS[i] = (ull*)p; p += (size_t)MAXNNZ * 8; }
    ull*    cpairS[2]; for (int i = 0; i < 2; ++i) { cpairS[i] = (ull*)p; p += (size_t)MAXNNZ * 8; }
    const size_t need_csr = p - (char*)d_ws;
    const bool csr_ok = (ws_size >= need_csr) && (nb <= NBMAX) && (N < (1 << 17));
    (void)n_in; (void)out_size;

    // --- degree / dinv ---
    (void)hipMemsetAsync(cnt, 0, (size_t)N * sizeof(int), stream);
    hist_kernel<<<(E + 255) / 256, 256, 0, stream>>>(edge_index + E, cnt, E);
    dinv_kernel<<<(N + 255) / 256, 256, 0, stream>>>(cnt, dinv, N);

    // --- dual GEMM + rownorm ---
    gemm_fused<<<dim3((N + 63) / 64, 4), 256, 0, stream>>>(
        x, lin_w, lin_b, gw_w, out1, xwh, N);
    rownorm_kernel<<<(N + 3) / 4, 256, 0, stream>>>(out1, N);

    if (csr_ok) {
        struct Op {
            const int* rows; const int* cols; const float* vals;
            int mode; int nnz;
            const __half* srch; const float* srcf; const float* init_src;
            float* dstf; __half* dsth;
        } ops[7];
        ops[0] = {edge_index, edge_index + E, nullptr, 2, E,
                  nullptr, out1, out1, out0, nullptr};
        for (int i = 0; i < 3; ++i) {
            const int* ri1 = phi_inv_idx + (size_t)i * 2 * NNZ;
            const int* ri2 = phi_idx + (size_t)i * 2 * NNZ;
            ops[1 + 2 * i] = {ri1, ri1 + NNZ, phi_inv_vals + (size_t)i * NNZ,
                              0, NNZ, xwh, nullptr, nullptr, nullptr, t1h};
            float*  bf = (i == 2) ? out1 : nullptr;
            __half* bh = (i == 0) ? z0h : (i == 1) ? z1h : nullptr;
            ops[2 + 2 * i] = {ri2, ri2 + NNZ, phi_vals + (size_t)i * NNZ,
                              1, NNZ, t1h, nullptr, nullptr, bf, bh};
        }

        auto scans = [&](int k) {   // cnt -> ptr[k%3]/cursor[k%2]/bcur[k%2]; zero cnt
            scan_reduce_kernel<<<nblk, 256, 0, stream>>>(cnt, bsum, N);
            scan_bsum_kernel<<<1, 64, 0, stream>>>(bsum, bofs, ptrS[k % 3], nblk, N);
            scan_block_kernel<<<nblk, 256, 0, stream>>>(cnt, bofs, ptrS[k % 3],
                                                        curS[k & 1], N);
            bcur_init_kernel<<<1, NBMAX, 0, stream>>>(ptrS[k % 3], bcurS[k & 1], N, nb);
        };

        const int GRID = 2048;
        // prologue: hist(0); scans(0); [A(0) || H(1)]; scans(1)
        hist_kernel<<<(ops[0].nnz + 255) / 256, 256, 0, stream>>>(
            ops[0].rows, cnt, ops[0].nnz);
        scans(0);
        fused2_kernel<<<GRID, 256, 0, stream>>>(
            nullptr, nullptr, nullptr, nullptr, nullptr, dinv, nullptr, nullptr, N, 0,
            nullptr, nullptr, nullptr, nullptr, 0, nb,
            ops[0].rows, ops[0].cols, ops[0].vals, diag_w, ops[0].mode,
            bcurS[0], stagS[0], ops[0].nnz,
            ops[1].rows, cnt, ops[1].nnz, 2);
        scans(1);

        // F_j = G(j-1) || B(j) || A(j+1) || H(j+2)
        for (int j = 0; j <= 7; ++j) {
            const Op* g = (j >= 1) ? &ops[j - 1] : nullptr;
            const Op* b = (j <= 6) ? &ops[j] : nullptr;
            const Op* a = (j + 1 <= 6) ? &ops[j + 1] : nullptr;
            const Op* h = (j + 2 <= 6) ? &ops[j + 2] : nullptr;
            int mix = (j == 0) ? 3 : (j == 7) ? 0 : 1;
            fused2_kernel<<<GRID, 256, 0, stream>>>(
                g ? ptrS[(j - 1) % 3] : nullptr,
                g ? (const int2*)cpairS[(j - 1) & 1] : nullptr,
                g ? g->srch : nullptr, g ? g->srcf : nullptr,
                g ? g->init_src : nullptr, dinv,
                g ? g->dstf : nullptr, g ? g->dsth : nullptr, N, g ? g->nnz : 0,
                b ? stagS[j & 1] : nullptr, b ? ptrS[j % 3] : nullptr,
                b ? curS[j & 1] : nullptr, b ? cpairS[j & 1] : nullptr,
                b ? b->nnz : 0, nb,
                a ? a->rows : nullptr, a ? a->cols : nullptr,
                a ? a->vals : nullptr, diag_w, a ? a->mode : 0,
                a ? bcurS[(j + 1) & 1] : nullptr, a ? stagS[(j + 1) & 1] : nullptr,
                a ? a->nnz : 0,
                h ? h->rows : nullptr, cnt, h ? h->nnz : 0,
                mix);
            if (j + 2 <= 6) scans(j + 2);
        }

        // --- attention pooling, in place on out1 ---
        attn_h_kernel<<<2048, 256, 0, stream>>>(z0h, z1h, out1, att_w1, att_b1,
                                                att_w2, out1, N);
    } else {
        // --------- fallback: atomic scatter path (fp32 z) ---------
        float*  z0f  = (float*)tail;
        float*  z1f  = z0f + NF;
        float*  t1f  = z1f + NF;
        __half* t1hf = (__half*)(t1f + NF);
        __half* xhf  = t1hf + NF;
        f2h_kernel<<<((NF / 2) + 255) / 256, 256, 0, stream>>>(out1, xhf, NF / 2);
        for (int i = 0; i < 3; ++i) {
            const int* ri1 = phi_inv_idx + (size_t)i * 2 * NNZ;
            const int* ci1 = ri1 + NNZ;
            const int* ri2 = phi_idx + (size_t)i * 2 * NNZ;
            const int* ci2 = ri2 + NNZ;
            float* zdst = (i == 0) ? z0f : (i == 1) ? z1f : out0;

            (void)hipMemsetAsync(t1f, 0, NF * sizeof(float), stream);
            spmm_h_kernel<<<(NNZ + 3) / 4, 256, 0, stream>>>(
                ri1, ci1, phi_inv_vals + (size_t)i * NNZ, nullptr, xwh, t1f, NNZ);
            f2h_kernel<<<((NF / 2) + 255) / 256, 256, 0, stream>>>(t1f, t1hf,
                                                                   NF / 2);
            (void)hipMemsetAsync(zdst, 0, NF * sizeof(float), stream);
            spmm_h_kernel<<<(NNZ + 3) / 4, 256, 0, stream>>>(
                ri2, ci2, phi_vals + (size_t)i * NNZ, diag_w, t1hf, zdst, NNZ);
        }
        attn_f_kernel<<<2048, 256, 0, stream>>>(z0f, z1f, out0, att_w1, att_b1,
                                                att_w2, t1f, N);
        appnp_init_kernel<<<((size_t)N * 32 + 255) / 256, 256, 0, stream>>>(
            out1, dinv, out0, N);
        appnp_edge_h_kernel<<<(E + 3) / 4, 256, 0, stream>>>(
            edge_index, edge_index + E, dinv, xhf, out0, E);
        (void)hipMemcpyAsync(out1, t1f, NF * sizeof(float),
                             hipMemcpyDeviceToDevice, stream);
    }
}